// Round 11
// baseline (207.814 us; speedup 1.0000x reference)
//
#include <hip/hip_runtime.h>
#include <math.h>

#define HQ   12
#define DH   64
#define NSEQ 1024
#define BB   4
#define DIMM 768
#define RR   8
#define BHD  (BB*HQ)      // 48
#define MROWS (BB*NSEQ)   // 4096
#define OUT_ELEMS (BB*NSEQ*DIMM)  // 3145728

typedef short bf16x8 __attribute__((ext_vector_type(8)));
typedef float f32x4  __attribute__((ext_vector_type(4)));

__device__ __forceinline__ unsigned short f2bf(float f) {
    union { float f; unsigned u; } x; x.f = f;
    return (unsigned short)((x.u + 0x7fffu + ((x.u >> 16) & 1u)) >> 16);
}
__device__ __forceinline__ float bf2f(unsigned short b) {
    union { unsigned u; float f; } x; x.u = ((unsigned)b) << 16;
    return x.f;
}
// pack two fp32 -> bf16 pair (lo=w0, hi=w1) with +0x8000 rounding, 3 insts
__device__ __forceinline__ unsigned pack_bf16(float w0, float w1) {
    return __builtin_amdgcn_perm(__float_as_uint(w1) + 0x8000u,
                                 __float_as_uint(w0) + 0x8000u, 0x07060302u);
}

#define AS_GLOBAL(p) ((const __attribute__((address_space(1))) void*)(p))
#define AS_LDS(p)    ((__attribute__((address_space(3))) void*)(p))

// ---------------------------------------------------------------------------
// prep: seg 0-2 convert x/wv/wo to bf16; seg 3-6 KL partials -> 256 unique
// double slots (no atomics, no init); seg 7 combine Cqk (576 blocks).
// ---------------------------------------------------------------------------
__global__ __launch_bounds__(256)
void prep_kernel(const float* __restrict__ x,  const float* __restrict__ wv,
                 const float* __restrict__ wo, const float* __restrict__ wq,
                 const float* __restrict__ wq_ls, const float* __restrict__ wk,
                 const float* __restrict__ wk_ls, const float* __restrict__ wv_ls,
                 const float* __restrict__ wo_ls, const float* __restrict__ sqw,
                 const float* __restrict__ skw,
                 unsigned short* __restrict__ xb, unsigned short* __restrict__ wvb,
                 unsigned short* __restrict__ wob, unsigned short* __restrict__ cqk,
                 double* __restrict__ klparts)
{
    __shared__ double sd[256];
    const int seg = blockIdx.y;
    const int tid = threadIdx.x;
    const int bx  = blockIdx.x;

    if (seg <= 2) {
        const float* src = (seg == 0) ? x : (seg == 1) ? wv : wo;
        unsigned short* dst = (seg == 0) ? xb : (seg == 1) ? wvb : wob;
        const int n4 = (seg == 0) ? 786432 : 147456;
        for (int i = bx*256 + tid; i < n4; i += 576*256) {
            float4 v = ((const float4*)src)[i];
            ((uint2*)dst)[i] = make_uint2(pack_bf16(v.x, v.y), pack_bf16(v.z, v.w));
        }
    } else if (seg <= 6) {
        if (bx >= 64) return;
        const float *mu, *ls;
        if      (seg == 3) { mu = wq; ls = wq_ls; }
        else if (seg == 4) { mu = wk; ls = wk_ls; }
        else if (seg == 5) { mu = wv; ls = wv_ls; }
        else               { mu = wo; ls = wo_ls; }
        double acc = 0.0;
        for (int i = bx*256 + tid; i < 147456; i += 64*256) {
            float4 m4 = ((const float4*)mu)[i];
            float4 l4 = ((const float4*)ls)[i];
            acc += (double)(expf(2.f*l4.x) + m4.x*m4.x - 1.f - 2.f*l4.x);
            acc += (double)(expf(2.f*l4.y) + m4.y*m4.y - 1.f - 2.f*l4.y);
            acc += (double)(expf(2.f*l4.z) + m4.z*m4.z - 1.f - 2.f*l4.z);
            acc += (double)(expf(2.f*l4.w) + m4.w*m4.w - 1.f - 2.f*l4.w);
        }
        sd[tid] = acc;
        __syncthreads();
        for (int s = 128; s > 0; s >>= 1) {
            if (tid < s) sd[tid] += sd[tid + s];
            __syncthreads();
        }
        if (tid == 0) klparts[(seg - 3)*64 + bx] = sd[0];
    } else {
        const int j   = (bx % 3)*256 + tid;
        const int row = bx / 3;                  // 0..191
        const int g   = row >= 96;
        const int hr  = row - g*96;
        const int h   = hr >> 3, r = hr & 7;
        const float* sw = (g ? skw : sqw) + r*64;
        const float* W  = (g ? wk  : wq) + h*64*768 + j;
        float acc = 0.f;
        #pragma unroll
        for (int d = 0; d < 64; ++d) acc += sw[d] * W[d*768];
        cqk[row*768 + j] = f2bf(acc);
    }
}

// ---------------------------------------------------------------------------
// proj_kernel: fused V-GEMM + lspd-GEMM, grid (15,64). 64x64 tiles, BK=32,
// single-buffer 2-barrier K-loop (the proven R8 structure).
//   bx < 12 : V-proj, A/B swapped (acc=C^T) -> vt bf16 (bh,d,n)
//   bx >= 12: spd_pre = x . Cqk^T; epilogue softplus->log->bf16 + norms
// ---------------------------------------------------------------------------
__global__ __launch_bounds__(256)
void proj_kernel(const unsigned short* __restrict__ X,
                 const unsigned short* __restrict__ Wv,
                 const unsigned short* __restrict__ Cqk,
                 const float* __restrict__ sqb, const float* __restrict__ skb,
                 unsigned short* __restrict__ vt,
                 unsigned short* __restrict__ lqo, unsigned short* __restrict__ lko,
                 float* __restrict__ nqo, float* __restrict__ nko)
{
    __shared__ unsigned short As[64*32];    // 4 KB
    __shared__ unsigned short Bs[64*32];    // 4 KB
    const int tid  = threadIdx.x;
    const int lane = tid & 63;
    const int qr   = lane & 15, quad = lane >> 4;
    const int wid  = tid >> 6;
    const int w_m  = wid >> 1, w_n = wid & 1;
    const int bx = blockIdx.x, by = blockIdx.y;

    const bool vrole = (bx < 12);
    const unsigned short* Abase = vrole ? (Wv + bx*64*768) : (X + by*64*768);
    const unsigned short* Bbase = vrole ? (X + by*64*768)  : (Cqk + (bx-12)*64*768);

    const int row0 = tid >> 2;
    const int segk = (tid & 3) * 8;

    f32x4 acc[2][2] = {};

    for (int kt = 0; kt < 768; kt += 32) {
        __syncthreads();
        __builtin_amdgcn_global_load_lds(AS_GLOBAL(Abase + row0*768 + kt + segk),
                                         AS_LDS(&As[tid*8]), 16, 0, 0);
        __builtin_amdgcn_global_load_lds(AS_GLOBAL(Bbase + row0*768 + kt + segk),
                                         AS_LDS(&Bs[tid*8]), 16, 0, 0);
        __syncthreads();

        bf16x8 a[2], b[2];
        #pragma unroll
        for (int mi = 0; mi < 2; ++mi)
            a[mi] = *(const bf16x8*)&As[(w_m*32 + mi*16 + qr)*32 + quad*8];
        #pragma unroll
        for (int ni = 0; ni < 2; ++ni)
            b[ni] = *(const bf16x8*)&Bs[(w_n*32 + ni*16 + qr)*32 + quad*8];
        #pragma unroll
        for (int mi = 0; mi < 2; ++mi)
            #pragma unroll
            for (int ni = 0; ni < 2; ++ni)
                acc[mi][ni] = __builtin_amdgcn_mfma_f32_16x16x32_bf16(a[mi], b[ni], acc[mi][ni], 0, 0, 0);
    }

    if (vrole) {
        const int bidx = (by*64) >> 10;              // batch (uniform per by)
        #pragma unroll
        for (int mi = 0; mi < 2; ++mi) {
            #pragma unroll
            for (int r = 0; r < 4; ++r) {
                const int i = bx*64 + w_m*32 + mi*16 + quad*4 + r;  // V channel
                const int h = i >> 6, d = i & 63;
                #pragma unroll
                for (int ni = 0; ni < 2; ++ni) {
                    const int n = by*64 + w_n*32 + ni*16 + qr;      // seq (global)
                    vt[((((bidx*HQ + h) << 6) + d) << 10) + (n & 1023)] = f2bf(acc[mi][ni][r]);
                }
            }
        }
    } else {
        const int rr = qr & 7;
        #pragma unroll
        for (int ni = 0; ni < 2; ++ni) {
            const int c = (bx-12)*64 + w_n*32 + ni*16 + qr;   // 0..191
            const int g = (c >= 96);                          // uniform per 16-grp
            const int cc = c - g*96;
            const int h = cc >> 3;
            unsigned short* dst = g ? lko : lqo;
            float* ndst = g ? nko : nqo;
            const float bias = (g ? skb : sqb)[rr];
            #pragma unroll
            for (int mi = 0; mi < 2; ++mi) {
                #pragma unroll
                for (int r = 0; r < 4; ++r) {
                    const int m = by*64 + w_m*32 + mi*16 + quad*4 + r;
                    const int b = m >> 10, n = m & 1023;
                    const float pre = acc[mi][ni][r] + bias;
                    const float sp = (pre > 0.f) ? (pre + log1pf(__expf(-pre)))
                                                 : log1pf(__expf(pre));
                    const float l = __logf(sp + 1e-6f + 1e-8f);
                    const unsigned short lb = f2bf(l);
                    const int base = ((b*HQ + h) << 10) + n;
                    dst[(base << 3) + rr] = lb;
                    const float lr = bf2f(lb);
                    float sq = lr * lr;
                    sq += __shfl_xor(sq, 1);
                    sq += __shfl_xor(sq, 2);
                    sq += __shfl_xor(sq, 4);
                    if (rr == 0) ndst[base] = sq;
                }
            }
        }
    }
}

// ---------------------------------------------------------------------------
// O-proj GEMM, 64x64 tiles, grid (12,64), single-buffer 2-barrier K-loop.
// out fp32 + bias; block (0,0) reduces the 256 KL partials and writes scalar.
// ---------------------------------------------------------------------------
__global__ __launch_bounds__(256)
void ogemm_kernel(const unsigned short* __restrict__ X,
                  const unsigned short* __restrict__ Wf,
                  const float* __restrict__ bias, float* __restrict__ outp,
                  const double* __restrict__ klparts)
{
    __shared__ unsigned short As[64*32];
    __shared__ unsigned short Bs[64*32];
    __shared__ double sd[256];
    const int tid  = threadIdx.x;
    const int lane = tid & 63;
    const int qr   = lane & 15, quad = lane >> 4;
    const int wid  = tid >> 6;
    const int w_m  = wid >> 1, w_n = wid & 1;
    const int bx = blockIdx.x, by = blockIdx.y;

    const unsigned short* Abase = X  + by*64*768;
    const unsigned short* Bbase = Wf + bx*64*768;
    const int row0 = tid >> 2;
    const int segk = (tid & 3) * 8;

    f32x4 acc[2][2] = {};

    for (int kt = 0; kt < 768; kt += 32) {
        __syncthreads();
        __builtin_amdgcn_global_load_lds(AS_GLOBAL(Abase + row0*768 + kt + segk),
                                         AS_LDS(&As[tid*8]), 16, 0, 0);
        __builtin_amdgcn_global_load_lds(AS_GLOBAL(Bbase + row0*768 + kt + segk),
                                         AS_LDS(&Bs[tid*8]), 16, 0, 0);
        __syncthreads();

        bf16x8 a[2], b[2];
        #pragma unroll
        for (int mi = 0; mi < 2; ++mi)
            a[mi] = *(const bf16x8*)&As[(w_m*32 + mi*16 + qr)*32 + quad*8];
        #pragma unroll
        for (int ni = 0; ni < 2; ++ni)
            b[ni] = *(const bf16x8*)&Bs[(w_n*32 + ni*16 + qr)*32 + quad*8];
        #pragma unroll
        for (int mi = 0; mi < 2; ++mi)
            #pragma unroll
            for (int ni = 0; ni < 2; ++ni)
                acc[mi][ni] = __builtin_amdgcn_mfma_f32_16x16x32_bf16(a[mi], b[ni], acc[mi][ni], 0, 0, 0);
    }

    #pragma unroll
    for (int ni = 0; ni < 2; ++ni) {
        const int i = bx*64 + w_n*32 + ni*16 + qr;
        const float bs = bias[i];
        #pragma unroll
        for (int mi = 0; mi < 2; ++mi) {
            const int m0 = by*64 + w_m*32 + mi*16 + quad*4;
            #pragma unroll
            for (int r = 0; r < 4; ++r)
                outp[(m0 + r)*768 + i] = acc[mi][ni][r] + bs;
        }
    }

    if (bx == 0 && by == 0) {
        sd[tid] = klparts[tid];
        __syncthreads();
        for (int s = 128; s > 0; s >>= 1) {
            if (tid < s) sd[tid] += sd[tid + s];
            __syncthreads();
        }
        if (tid == 0) outp[OUT_ELEMS] = (float)(0.5 * sd[0]);
    }
}

// ---------------------------------------------------------------------------
// Attention v6: 128-thread / 32-query blocks, grid (32,48) = 1536 blocks ->
// 6 co-resident blocks/CU (2x independent barrier domains vs R10; same
// per-wave work & LDS op count). Single-buffer 2-barrier staging per chunk.
// ---------------------------------------------------------------------------
__global__ __launch_bounds__(128)
void attn_kernel(const unsigned short* __restrict__ lq,
                 const unsigned short* __restrict__ lk,
                 const float* __restrict__ nq, const float* __restrict__ nk,
                 const unsigned short* __restrict__ vt,
                 unsigned short* __restrict__ out)
{
    __shared__ unsigned short lk_s[64*8];    // 1 KB
    __shared__ unsigned short vt_s[64*64];   // 8 KB, swizzled
    __shared__ unsigned short w_s[32*72];    // 4.5 KB, stride 72

    const int tid  = threadIdx.x;            // 0..127
    const int lane = tid & 63;
    const int wid  = tid >> 6;               // 0..1
    const int qr   = lane & 15;
    const int quad = lane >> 4;
    const int bh   = blockIdx.y;
    const int q0   = blockIdx.x*32 + wid*16;
    const int qrow = (bh << 10) + q0 + qr;
    const int bb   = bh / HQ;
    const int hh   = bh - bb*HQ;

    bf16x8 bq = {};
    if (quad == 0) bq = *(const bf16x8*)(lq + qrow*8);
    const float nqv = nq[qrow];

    f32x4 acc[4] = {};
    float wsum_acc = 0.f;

    const unsigned short* vtg = vt + (bh << 16);   // bh*64*1024
    const unsigned short* lkg = lk + (bh << 13);   // bh*1024*8
    const float*          nkg = nk + (bh << 10);

    const float EXP2S = -0.1803368801f;            // -0.125 * log2(e)

    for (int c = 0; c < NSEQ; c += 64) {
        __syncthreads();
        // stage vt chunk: 512 16B-slots, 4 per thread, XOR-swizzled groups
        #pragma unroll
        for (int u = 0; u < 4; ++u) {
            const int slot = tid + u*128;
            const int srow = slot >> 3;
            const int scol = ((slot & 7) ^ (srow & 7)) << 3;
            __builtin_amdgcn_global_load_lds(AS_GLOBAL(vtg + srow*1024 + c + scol),
                                             AS_LDS(&vt_s[slot*8]), 16, 0, 0);
        }
        if (tid < 64)
            __builtin_amdgcn_global_load_lds(AS_GLOBAL(lkg + (c + tid)*8),
                                             AS_LDS(&lk_s[tid*8]), 16, 0, 0);
        __syncthreads();

        float wsum_c = 0.f;
        unsigned wpk[4][2];
        #pragma unroll
        for (int kb = 0; kb < 4; ++kb) {
            bf16x8 ak = {};
            if (quad == 0) ak = *(const bf16x8*)&lk_s[(kb*16 + qr)*8];
            f32x4 s = {};
            s = __builtin_amdgcn_mfma_f32_16x16x32_bf16(ak, bq, s, 0, 0, 0);
            const float4 nk4 = *(const float4*)(nkg + c + kb*16 + quad*4);
            const float nkv[4] = {nk4.x, nk4.y, nk4.z, nk4.w};
            float w[4];
            #pragma unroll
            for (int r = 0; r < 4; ++r) {
                const float d2 = fmaf(-2.f, s[r], nqv + nkv[r]);
                const float dist = __builtin_amdgcn_sqrtf(fmaxf(d2, 1e-12f));
                w[r] = exp2f(dist * EXP2S);
                wsum_c += w[r];
            }
            wpk[kb][0] = pack_bf16(w[0], w[1]);
            wpk[kb][1] = pack_bf16(w[2], w[3]);
        }
        #pragma unroll
        for (int kb = 0; kb < 4; ++kb)
            *(uint2*)&w_s[(wid*16 + qr)*72 + kb*16 + quad*4] =
                make_uint2(wpk[kb][0], wpk[kb][1]);
        wsum_c += __shfl_xor(wsum_c, 16);
        wsum_c += __shfl_xor(wsum_c, 32);
        wsum_acc += wsum_c;

        #pragma unroll
        for (int s2 = 0; s2 < 2; ++s2) {
            const bf16x8 af = *(const bf16x8*)&w_s[(wid*16 + qr)*72 + s2*32 + quad*8];
            #pragma unroll
            for (int jb = 0; jb < 4; ++jb) {
                const int row = jb*16 + qr;
                const int grp = (s2*4 + quad) ^ (qr & 7);
                const bf16x8 bv = *(const bf16x8*)&vt_s[(row << 6) + (grp << 3)];
                acc[jb] = __builtin_amdgcn_mfma_f32_16x16x32_bf16(af, bv, acc[jb], 0, 0, 0);
            }
        }
    }

    const float inv = 1.0f / wsum_acc;   // lane's own q = qr
    #pragma unroll
    for (int jb = 0; jb < 4; ++jb) {
        #pragma unroll
        for (int r = 0; r < 4; ++r) {
            const int row = quad*4 + r;
            const float wi = __shfl(inv, row);
            const int qgl = q0 + row;
            const int d = jb*16 + qr;
            out[((bb << 10) + qgl)*768 + hh*64 + d] = f2bf(acc[jb][r] * wi);
        }
    }
}

// ---------------------------------------------------------------------------
extern "C" void kernel_launch(void* const* d_in, const int* in_sizes, int n_in,
                              void* d_out, int out_size, void* d_ws, size_t ws_size,
                              hipStream_t stream)
{
    const float* x     = (const float*)d_in[0];
    const float* wq    = (const float*)d_in[1];
    const float* wq_ls = (const float*)d_in[2];
    const float* wk    = (const float*)d_in[3];
    const float* wk_ls = (const float*)d_in[4];
    const float* wv    = (const float*)d_in[5];
    const float* wv_ls = (const float*)d_in[6];
    const float* wo    = (const float*)d_in[7];
    const float* wo_ls = (const float*)d_in[8];
    const float* wo_b  = (const float*)d_in[9];
    const float* sq_w  = (const float*)d_in[10];
    const float* sq_b  = (const float*)d_in[11];
    const float* sk_w  = (const float*)d_in[12];
    const float* sk_b  = (const float*)d_in[13];
    float* out = (float*)d_out;

    float* ws = (float*)d_ws;
    unsigned short* vt  = (unsigned short*)ws;                 // 1572864 f
    unsigned short* xb  = (unsigned short*)(ws + 1572864);     // 1572864 f (re-used as attn out)
    unsigned short* wvb = (unsigned short*)(ws + 3145728);     // 294912 f
    unsigned short* wob = (unsigned short*)(ws + 3440640);     // 294912 f
    unsigned short* cqk = (unsigned short*)(ws + 3735552);     // 73728 f
    unsigned short* lqb = (unsigned short*)(ws + 3809280);     // 196608 f
    unsigned short* lkb = (unsigned short*)(ws + 4005888);     // 196608 f
    float* nqb = ws + 4202496;                                 // 49152 f
    float* nkb = ws + 4251648;                                 // 49152 f
    double* klparts = (double*)(ws + 4300800);                 // 256 doubles

    prep_kernel<<<dim3(576, 8), dim3(256), 0, stream>>>(
        x, wv, wo, wq, wq_ls, wk, wk_ls, wv_ls, wo_ls, sq_w, sk_w,
        xb, wvb, wob, cqk, klparts);
    proj_kernel<<<dim3(15, 64), dim3(256), 0, stream>>>(xb, wvb, cqk, sq_b, sk_b,
                                                        vt, lqb, lkb, nqb, nkb);
    attn_kernel<<<dim3(32, BHD), dim3(128), 0, stream>>>(lqb, lkb, nqb, nkb, vt, xb);
    ogemm_kernel<<<dim3(12, 64), dim3(256), 0, stream>>>(xb, wob, wo_b, out, klparts);
}

// Round 12
// 195.564 us; speedup vs baseline: 1.0626x; 1.0626x over previous
//
#include <hip/hip_runtime.h>
#include <math.h>

#define HQ   12
#define DH   64
#define NSEQ 1024
#define BB   4
#define DIMM 768
#define RR   8
#define BHD  (BB*HQ)      // 48
#define MROWS (BB*NSEQ)   // 4096
#define OUT_ELEMS (BB*NSEQ*DIMM)  // 3145728

typedef short bf16x8 __attribute__((ext_vector_type(8)));
typedef float f32x4  __attribute__((ext_vector_type(4)));

__device__ __forceinline__ unsigned short f2bf(float f) {
    union { float f; unsigned u; } x; x.f = f;
    return (unsigned short)((x.u + 0x7fffu + ((x.u >> 16) & 1u)) >> 16);
}
__device__ __forceinline__ float bf2f(unsigned short b) {
    union { unsigned u; float f; } x; x.u = ((unsigned)b) << 16;
    return x.f;
}
// pack two fp32 -> bf16 pair (lo=w0, hi=w1) with +0x8000 rounding, 3 insts
__device__ __forceinline__ unsigned pack_bf16(float w0, float w1) {
    return __builtin_amdgcn_perm(__float_as_uint(w1) + 0x8000u,
                                 __float_as_uint(w0) + 0x8000u, 0x07060302u);
}

#define AS_GLOBAL(p) ((const __attribute__((address_space(1))) void*)(p))
#define AS_LDS(p)    ((__attribute__((address_space(3))) void*)(p))

// ---------------------------------------------------------------------------
// prep: seg 0-2 convert x/wv/wo to bf16; seg 3-6 KL partials -> 256 unique
// double slots (no atomics, no init); seg 7 combine Cqk (576 blocks).
// ---------------------------------------------------------------------------
__global__ __launch_bounds__(256)
void prep_kernel(const float* __restrict__ x,  const float* __restrict__ wv,
                 const float* __restrict__ wo, const float* __restrict__ wq,
                 const float* __restrict__ wq_ls, const float* __restrict__ wk,
                 const float* __restrict__ wk_ls, const float* __restrict__ wv_ls,
                 const float* __restrict__ wo_ls, const float* __restrict__ sqw,
                 const float* __restrict__ skw,
                 unsigned short* __restrict__ xb, unsigned short* __restrict__ wvb,
                 unsigned short* __restrict__ wob, unsigned short* __restrict__ cqk,
                 double* __restrict__ klparts)
{
    __shared__ double sd[256];
    const int seg = blockIdx.y;
    const int tid = threadIdx.x;
    const int bx  = blockIdx.x;

    if (seg <= 2) {
        const float* src = (seg == 0) ? x : (seg == 1) ? wv : wo;
        unsigned short* dst = (seg == 0) ? xb : (seg == 1) ? wvb : wob;
        const int n4 = (seg == 0) ? 786432 : 147456;
        for (int i = bx*256 + tid; i < n4; i += 576*256) {
            float4 v = ((const float4*)src)[i];
            ((uint2*)dst)[i] = make_uint2(pack_bf16(v.x, v.y), pack_bf16(v.z, v.w));
        }
    } else if (seg <= 6) {
        if (bx >= 64) return;
        const float *mu, *ls;
        if      (seg == 3) { mu = wq; ls = wq_ls; }
        else if (seg == 4) { mu = wk; ls = wk_ls; }
        else if (seg == 5) { mu = wv; ls = wv_ls; }
        else               { mu = wo; ls = wo_ls; }
        double acc = 0.0;
        for (int i = bx*256 + tid; i < 147456; i += 64*256) {
            float4 m4 = ((const float4*)mu)[i];
            float4 l4 = ((const float4*)ls)[i];
            acc += (double)(expf(2.f*l4.x) + m4.x*m4.x - 1.f - 2.f*l4.x);
            acc += (double)(expf(2.f*l4.y) + m4.y*m4.y - 1.f - 2.f*l4.y);
            acc += (double)(expf(2.f*l4.z) + m4.z*m4.z - 1.f - 2.f*l4.z);
            acc += (double)(expf(2.f*l4.w) + m4.w*m4.w - 1.f - 2.f*l4.w);
        }
        sd[tid] = acc;
        __syncthreads();
        for (int s = 128; s > 0; s >>= 1) {
            if (tid < s) sd[tid] += sd[tid + s];
            __syncthreads();
        }
        if (tid == 0) klparts[(seg - 3)*64 + bx] = sd[0];
    } else {
        const int j   = (bx % 3)*256 + tid;
        const int row = bx / 3;                  // 0..191
        const int g   = row >= 96;
        const int hr  = row - g*96;
        const int h   = hr >> 3, r = hr & 7;
        const float* sw = (g ? skw : sqw) + r*64;
        const float* W  = (g ? wk  : wq) + h*64*768 + j;
        float acc = 0.f;
        #pragma unroll
        for (int d = 0; d < 64; ++d) acc += sw[d] * W[d*768];
        cqk[row*768 + j] = f2bf(acc);
    }
}

// ---------------------------------------------------------------------------
// proj_kernel: fused V-GEMM + lspd-GEMM, grid (15,64). 64x64 tiles, BK=32,
// single-buffer 2-barrier K-loop (the proven R8 structure).
//   bx < 12 : V-proj, A/B swapped (acc=C^T) -> vt bf16 (bh,d,n)
//   bx >= 12: spd_pre = x . Cqk^T; epilogue softplus->log->bf16 + norms
// ---------------------------------------------------------------------------
__global__ __launch_bounds__(256)
void proj_kernel(const unsigned short* __restrict__ X,
                 const unsigned short* __restrict__ Wv,
                 const unsigned short* __restrict__ Cqk,
                 const float* __restrict__ sqb, const float* __restrict__ skb,
                 unsigned short* __restrict__ vt,
                 unsigned short* __restrict__ lqo, unsigned short* __restrict__ lko,
                 float* __restrict__ nqo, float* __restrict__ nko)
{
    __shared__ unsigned short As[64*32];    // 4 KB
    __shared__ unsigned short Bs[64*32];    // 4 KB
    const int tid  = threadIdx.x;
    const int lane = tid & 63;
    const int qr   = lane & 15, quad = lane >> 4;
    const int wid  = tid >> 6;
    const int w_m  = wid >> 1, w_n = wid & 1;
    const int bx = blockIdx.x, by = blockIdx.y;

    const bool vrole = (bx < 12);
    const unsigned short* Abase = vrole ? (Wv + bx*64*768) : (X + by*64*768);
    const unsigned short* Bbase = vrole ? (X + by*64*768)  : (Cqk + (bx-12)*64*768);

    const int row0 = tid >> 2;
    const int segk = (tid & 3) * 8;

    f32x4 acc[2][2] = {};

    for (int kt = 0; kt < 768; kt += 32) {
        __syncthreads();
        __builtin_amdgcn_global_load_lds(AS_GLOBAL(Abase + row0*768 + kt + segk),
                                         AS_LDS(&As[tid*8]), 16, 0, 0);
        __builtin_amdgcn_global_load_lds(AS_GLOBAL(Bbase + row0*768 + kt + segk),
                                         AS_LDS(&Bs[tid*8]), 16, 0, 0);
        __syncthreads();

        bf16x8 a[2], b[2];
        #pragma unroll
        for (int mi = 0; mi < 2; ++mi)
            a[mi] = *(const bf16x8*)&As[(w_m*32 + mi*16 + qr)*32 + quad*8];
        #pragma unroll
        for (int ni = 0; ni < 2; ++ni)
            b[ni] = *(const bf16x8*)&Bs[(w_n*32 + ni*16 + qr)*32 + quad*8];
        #pragma unroll
        for (int mi = 0; mi < 2; ++mi)
            #pragma unroll
            for (int ni = 0; ni < 2; ++ni)
                acc[mi][ni] = __builtin_amdgcn_mfma_f32_16x16x32_bf16(a[mi], b[ni], acc[mi][ni], 0, 0, 0);
    }

    if (vrole) {
        const int bidx = (by*64) >> 10;              // batch (uniform per by)
        #pragma unroll
        for (int mi = 0; mi < 2; ++mi) {
            #pragma unroll
            for (int r = 0; r < 4; ++r) {
                const int i = bx*64 + w_m*32 + mi*16 + quad*4 + r;  // V channel
                const int h = i >> 6, d = i & 63;
                #pragma unroll
                for (int ni = 0; ni < 2; ++ni) {
                    const int n = by*64 + w_n*32 + ni*16 + qr;      // seq (global)
                    vt[((((bidx*HQ + h) << 6) + d) << 10) + (n & 1023)] = f2bf(acc[mi][ni][r]);
                }
            }
        }
    } else {
        const int rr = qr & 7;
        #pragma unroll
        for (int ni = 0; ni < 2; ++ni) {
            const int c = (bx-12)*64 + w_n*32 + ni*16 + qr;   // 0..191
            const int g = (c >= 96);                          // uniform per 16-grp
            const int cc = c - g*96;
            const int h = cc >> 3;
            unsigned short* dst = g ? lko : lqo;
            float* ndst = g ? nko : nqo;
            const float bias = (g ? skb : sqb)[rr];
            #pragma unroll
            for (int mi = 0; mi < 2; ++mi) {
                #pragma unroll
                for (int r = 0; r < 4; ++r) {
                    const int m = by*64 + w_m*32 + mi*16 + quad*4 + r;
                    const int b = m >> 10, n = m & 1023;
                    const float pre = acc[mi][ni][r] + bias;
                    const float sp = (pre > 0.f) ? (pre + log1pf(__expf(-pre)))
                                                 : log1pf(__expf(pre));
                    const float l = __logf(sp + 1e-6f + 1e-8f);
                    const unsigned short lb = f2bf(l);
                    const int base = ((b*HQ + h) << 10) + n;
                    dst[(base << 3) + rr] = lb;
                    const float lr = bf2f(lb);
                    float sq = lr * lr;
                    sq += __shfl_xor(sq, 1);
                    sq += __shfl_xor(sq, 2);
                    sq += __shfl_xor(sq, 4);
                    if (rr == 0) ndst[base] = sq;
                }
            }
        }
    }
}

// ---------------------------------------------------------------------------
// O-proj GEMM, 64x64 tiles, grid (12,64), single-buffer 2-barrier K-loop.
// out fp32 + bias; block (0,0) reduces the 256 KL partials and writes scalar.
// ---------------------------------------------------------------------------
__global__ __launch_bounds__(256)
void ogemm_kernel(const unsigned short* __restrict__ X,
                  const unsigned short* __restrict__ Wf,
                  const float* __restrict__ bias, float* __restrict__ outp,
                  const double* __restrict__ klparts)
{
    __shared__ unsigned short As[64*32];
    __shared__ unsigned short Bs[64*32];
    __shared__ double sd[256];
    const int tid  = threadIdx.x;
    const int lane = tid & 63;
    const int qr   = lane & 15, quad = lane >> 4;
    const int wid  = tid >> 6;
    const int w_m  = wid >> 1, w_n = wid & 1;
    const int bx = blockIdx.x, by = blockIdx.y;

    const unsigned short* Abase = X  + by*64*768;
    const unsigned short* Bbase = Wf + bx*64*768;
    const int row0 = tid >> 2;
    const int segk = (tid & 3) * 8;

    f32x4 acc[2][2] = {};

    for (int kt = 0; kt < 768; kt += 32) {
        __syncthreads();
        __builtin_amdgcn_global_load_lds(AS_GLOBAL(Abase + row0*768 + kt + segk),
                                         AS_LDS(&As[tid*8]), 16, 0, 0);
        __builtin_amdgcn_global_load_lds(AS_GLOBAL(Bbase + row0*768 + kt + segk),
                                         AS_LDS(&Bs[tid*8]), 16, 0, 0);
        __syncthreads();

        bf16x8 a[2], b[2];
        #pragma unroll
        for (int mi = 0; mi < 2; ++mi)
            a[mi] = *(const bf16x8*)&As[(w_m*32 + mi*16 + qr)*32 + quad*8];
        #pragma unroll
        for (int ni = 0; ni < 2; ++ni)
            b[ni] = *(const bf16x8*)&Bs[(w_n*32 + ni*16 + qr)*32 + quad*8];
        #pragma unroll
        for (int mi = 0; mi < 2; ++mi)
            #pragma unroll
            for (int ni = 0; ni < 2; ++ni)
                acc[mi][ni] = __builtin_amdgcn_mfma_f32_16x16x32_bf16(a[mi], b[ni], acc[mi][ni], 0, 0, 0);
    }

    #pragma unroll
    for (int ni = 0; ni < 2; ++ni) {
        const int i = bx*64 + w_n*32 + ni*16 + qr;
        const float bs = bias[i];
        #pragma unroll
        for (int mi = 0; mi < 2; ++mi) {
            const int m0 = by*64 + w_m*32 + mi*16 + quad*4;
            #pragma unroll
            for (int r = 0; r < 4; ++r)
                outp[(m0 + r)*768 + i] = acc[mi][ni][r] + bs;
        }
    }

    if (bx == 0 && by == 0) {
        sd[tid] = klparts[tid];
        __syncthreads();
        for (int s = 128; s > 0; s >>= 1) {
            if (tid < s) sd[tid] += sd[tid + s];
            __syncthreads();
        }
        if (tid == 0) outp[OUT_ELEMS] = (float)(0.5 * sd[0]);
    }
}

// ---------------------------------------------------------------------------
// Attention v7: 256 threads, 64 queries/block, grid (16,48) — R10 shape —
// but 128-key chunks (8 barriers instead of 16; per-chunk compute doubles,
// drain cost per chunk unchanged => exposed-latency share halves).
// LDS: lk 2 KB + vt 16 KB (16B-group XOR swizzle) + w_s 64x136 (17 KB).
// ---------------------------------------------------------------------------
__global__ __launch_bounds__(256)
void attn_kernel(const unsigned short* __restrict__ lq,
                 const unsigned short* __restrict__ lk,
                 const float* __restrict__ nq, const float* __restrict__ nk,
                 const unsigned short* __restrict__ vt,
                 unsigned short* __restrict__ out)
{
    __shared__ unsigned short lk_s[128*8];    // 2 KB
    __shared__ unsigned short vt_s[64*128];   // 16 KB, swizzled 16B groups
    __shared__ unsigned short w_s[64*136];    // 17 KB, stride 136 (4w mod 32)

    const int tid  = threadIdx.x;
    const int lane = tid & 63;
    const int wid  = tid >> 6;
    const int qr   = lane & 15;
    const int quad = lane >> 4;
    const int bh   = blockIdx.y;
    const int q0   = blockIdx.x*64 + wid*16;
    const int qrow = (bh << 10) + q0 + qr;
    const int bb   = bh / HQ;
    const int hh   = bh - bb*HQ;

    bf16x8 bq = {};
    if (quad == 0) bq = *(const bf16x8*)(lq + qrow*8);
    const float nqv = nq[qrow];

    f32x4 acc[4] = {};
    float wsum_acc = 0.f;

    const unsigned short* vtg = vt + (bh << 16);   // bh*64*1024
    const unsigned short* lkg = lk + (bh << 13);   // bh*1024*8
    const float*          nkg = nk + (bh << 10);

    const float EXP2S = -0.1803368801f;            // -0.125 * log2(e)

    for (int c = 0; c < NSEQ; c += 128) {
        __syncthreads();
        // vt staging: 1024 16B slots; slot s holds global group (s&15)^(row&7)
        // of row s>>4 (dest stays lane-contiguous; SOURCE is swizzled).
        #pragma unroll
        for (int u = 0; u < 4; ++u) {
            const int slot = tid + u*256;
            const int srow = slot >> 4;
            const int gg = ((slot & 15) ^ (srow & 7)) << 3;   // global col elem
            __builtin_amdgcn_global_load_lds(AS_GLOBAL(vtg + srow*1024 + c + gg),
                                             AS_LDS(&vt_s[slot*8]), 16, 0, 0);
        }
        if (tid < 128)
            __builtin_amdgcn_global_load_lds(AS_GLOBAL(lkg + (c + tid)*8),
                                             AS_LDS(&lk_s[tid*8]), 16, 0, 0);
        __syncthreads();

        float wsum_c = 0.f;
        unsigned wpk[8][2];
        #pragma unroll
        for (int kb = 0; kb < 8; ++kb) {
            bf16x8 ak = {};
            if (quad == 0) ak = *(const bf16x8*)&lk_s[(kb*16 + qr)*8];
            f32x4 s = {};
            s = __builtin_amdgcn_mfma_f32_16x16x32_bf16(ak, bq, s, 0, 0, 0);
            const float4 nk4 = *(const float4*)(nkg + c + kb*16 + quad*4);
            const float nkv[4] = {nk4.x, nk4.y, nk4.z, nk4.w};
            float w[4];
            #pragma unroll
            for (int r = 0; r < 4; ++r) {
                const float d2 = fmaf(-2.f, s[r], nqv + nkv[r]);
                const float dist = __builtin_amdgcn_sqrtf(fmaxf(d2, 1e-12f));
                w[r] = exp2f(dist * EXP2S);
                wsum_c += w[r];
            }
            wpk[kb][0] = pack_bf16(w[0], w[1]);
            wpk[kb][1] = pack_bf16(w[2], w[3]);
        }
        #pragma unroll
        for (int kb = 0; kb < 8; ++kb)
            *(uint2*)&w_s[(wid*16 + qr)*136 + kb*16 + quad*4] =
                make_uint2(wpk[kb][0], wpk[kb][1]);
        wsum_c += __shfl_xor(wsum_c, 16);
        wsum_c += __shfl_xor(wsum_c, 32);
        wsum_acc += wsum_c;

        #pragma unroll
        for (int s2 = 0; s2 < 4; ++s2) {
            const bf16x8 af = *(const bf16x8*)&w_s[(wid*16 + qr)*136 + s2*32 + quad*8];
            #pragma unroll
            for (int jb = 0; jb < 4; ++jb) {
                const int row = jb*16 + qr;
                const int grp = (s2*4 + quad) ^ (qr & 7);
                const bf16x8 bv = *(const bf16x8*)&vt_s[(row << 7) + (grp << 3)];
                acc[jb] = __builtin_amdgcn_mfma_f32_16x16x32_bf16(af, bv, acc[jb], 0, 0, 0);
            }
        }
    }

    const float inv = 1.0f / wsum_acc;   // lane's own q = qr
    #pragma unroll
    for (int jb = 0; jb < 4; ++jb) {
        #pragma unroll
        for (int r = 0; r < 4; ++r) {
            const int row = quad*4 + r;
            const float wi = __shfl(inv, row);
            const int qgl = q0 + row;
            const int d = jb*16 + qr;
            out[((bb << 10) + qgl)*768 + hh*64 + d] = f2bf(acc[jb][r] * wi);
        }
    }
}

// ---------------------------------------------------------------------------
extern "C" void kernel_launch(void* const* d_in, const int* in_sizes, int n_in,
                              void* d_out, int out_size, void* d_ws, size_t ws_size,
                              hipStream_t stream)
{
    const float* x     = (const float*)d_in[0];
    const float* wq    = (const float*)d_in[1];
    const float* wq_ls = (const float*)d_in[2];
    const float* wk    = (const float*)d_in[3];
    const float* wk_ls = (const float*)d_in[4];
    const float* wv    = (const float*)d_in[5];
    const float* wv_ls = (const float*)d_in[6];
    const float* wo    = (const float*)d_in[7];
    const float* wo_ls = (const float*)d_in[8];
    const float* wo_b  = (const float*)d_in[9];
    const float* sq_w  = (const float*)d_in[10];
    const float* sq_b  = (const float*)d_in[11];
    const float* sk_w  = (const float*)d_in[12];
    const float* sk_b  = (const float*)d_in[13];
    float* out = (float*)d_out;

    float* ws = (float*)d_ws;
    unsigned short* vt  = (unsigned short*)ws;                 // 1572864 f
    unsigned short* xb  = (unsigned short*)(ws + 1572864);     // 1572864 f (re-used as attn out)
    unsigned short* wvb = (unsigned short*)(ws + 3145728);     // 294912 f
    unsigned short* wob = (unsigned short*)(ws + 3440640);     // 294912 f
    unsigned short* cqk = (unsigned short*)(ws + 3735552);     // 73728 f
    unsigned short* lqb = (unsigned short*)(ws + 3809280);     // 196608 f
    unsigned short* lkb = (unsigned short*)(ws + 4005888);     // 196608 f
    float* nqb = ws + 4202496;                                 // 49152 f
    float* nkb = ws + 4251648;                                 // 49152 f
    double* klparts = (double*)(ws + 4300800);                 // 256 doubles

    prep_kernel<<<dim3(576, 8), dim3(256), 0, stream>>>(
        x, wv, wo, wq, wq_ls, wk, wk_ls, wv_ls, wo_ls, sq_w, sk_w,
        xb, wvb, wob, cqk, klparts);
    proj_kernel<<<dim3(15, 64), dim3(256), 0, stream>>>(xb, wvb, cqk, sq_b, sk_b,
                                                        vt, lqb, lkb, nqb, nkb);
    attn_kernel<<<dim3(16, BHD), dim3(256), 0, stream>>>(lqb, lkb, nqb, nkb, vt, xb);
    ogemm_kernel<<<dim3(12, 64), dim3(256), 0, stream>>>(xb, wob, wo_b, out, klparts);
}

// Round 13
// 188.286 us; speedup vs baseline: 1.1037x; 1.0387x over previous
//
#include <hip/hip_runtime.h>
#include <math.h>

#define HQ   12
#define DH   64
#define NSEQ 1024
#define BB   4
#define DIMM 768
#define RR   8
#define BHD  (BB*HQ)      // 48
#define MROWS (BB*NSEQ)   // 4096
#define OUT_ELEMS (BB*NSEQ*DIMM)  // 3145728

typedef short bf16x8 __attribute__((ext_vector_type(8)));
typedef float f32x4  __attribute__((ext_vector_type(4)));

__device__ __forceinline__ unsigned short f2bf(float f) {
    union { float f; unsigned u; } x; x.f = f;
    return (unsigned short)((x.u + 0x7fffu + ((x.u >> 16) & 1u)) >> 16);
}
__device__ __forceinline__ float bf2f(unsigned short b) {
    union { unsigned u; float f; } x; x.u = ((unsigned)b) << 16;
    return x.f;
}
// pack two fp32 -> bf16 pair (lo=w0, hi=w1) with +0x8000 rounding, 3 insts
__device__ __forceinline__ unsigned pack_bf16(float w0, float w1) {
    return __builtin_amdgcn_perm(__float_as_uint(w1) + 0x8000u,
                                 __float_as_uint(w0) + 0x8000u, 0x07060302u);
}

#define AS_GLOBAL(p) ((const __attribute__((address_space(1))) void*)(p))
#define AS_LDS(p)    ((__attribute__((address_space(3))) void*)(p))

// ---------------------------------------------------------------------------
// prep: seg 0-2 convert x/wv/wo to bf16; seg 3-6 KL partials -> 256 unique
// double slots (no atomics, no init); seg 7 combine Cqk (576 blocks).
// ---------------------------------------------------------------------------
__global__ __launch_bounds__(256)
void prep_kernel(const float* __restrict__ x,  const float* __restrict__ wv,
                 const float* __restrict__ wo, const float* __restrict__ wq,
                 const float* __restrict__ wq_ls, const float* __restrict__ wk,
                 const float* __restrict__ wk_ls, const float* __restrict__ wv_ls,
                 const float* __restrict__ wo_ls, const float* __restrict__ sqw,
                 const float* __restrict__ skw,
                 unsigned short* __restrict__ xb, unsigned short* __restrict__ wvb,
                 unsigned short* __restrict__ wob, unsigned short* __restrict__ cqk,
                 double* __restrict__ klparts)
{
    __shared__ double sd[256];
    const int seg = blockIdx.y;
    const int tid = threadIdx.x;
    const int bx  = blockIdx.x;

    if (seg <= 2) {
        const float* src = (seg == 0) ? x : (seg == 1) ? wv : wo;
        unsigned short* dst = (seg == 0) ? xb : (seg == 1) ? wvb : wob;
        const int n4 = (seg == 0) ? 786432 : 147456;
        for (int i = bx*256 + tid; i < n4; i += 576*256) {
            float4 v = ((const float4*)src)[i];
            ((uint2*)dst)[i] = make_uint2(pack_bf16(v.x, v.y), pack_bf16(v.z, v.w));
        }
    } else if (seg <= 6) {
        if (bx >= 64) return;
        const float *mu, *ls;
        if      (seg == 3) { mu = wq; ls = wq_ls; }
        else if (seg == 4) { mu = wk; ls = wk_ls; }
        else if (seg == 5) { mu = wv; ls = wv_ls; }
        else               { mu = wo; ls = wo_ls; }
        double acc = 0.0;
        for (int i = bx*256 + tid; i < 147456; i += 64*256) {
            float4 m4 = ((const float4*)mu)[i];
            float4 l4 = ((const float4*)ls)[i];
            acc += (double)(expf(2.f*l4.x) + m4.x*m4.x - 1.f - 2.f*l4.x);
            acc += (double)(expf(2.f*l4.y) + m4.y*m4.y - 1.f - 2.f*l4.y);
            acc += (double)(expf(2.f*l4.z) + m4.z*m4.z - 1.f - 2.f*l4.z);
            acc += (double)(expf(2.f*l4.w) + m4.w*m4.w - 1.f - 2.f*l4.w);
        }
        sd[tid] = acc;
        __syncthreads();
        for (int s = 128; s > 0; s >>= 1) {
            if (tid < s) sd[tid] += sd[tid + s];
            __syncthreads();
        }
        if (tid == 0) klparts[(seg - 3)*64 + bx] = sd[0];
    } else {
        const int j   = (bx % 3)*256 + tid;
        const int row = bx / 3;                  // 0..191
        const int g   = row >= 96;
        const int hr  = row - g*96;
        const int h   = hr >> 3, r = hr & 7;
        const float* sw = (g ? skw : sqw) + r*64;
        const float* W  = (g ? wk  : wq) + h*64*768 + j;
        float acc = 0.f;
        #pragma unroll
        for (int d = 0; d < 64; ++d) acc += sw[d] * W[d*768];
        cqk[row*768 + j] = f2bf(acc);
    }
}

// ---------------------------------------------------------------------------
// proj_kernel: fused V-GEMM + lspd-GEMM, grid (15,64). 64x64 tiles, BK=64
// (12 drain-barriers instead of 24), XOR-16B-group swizzled LDS
// (group' = group ^ (row&7)) for conflict-free ds_read_b128.
//   bx < 12 : V-proj, A/B swapped (acc=C^T) -> vt bf16 (bh,d,n)
//   bx >= 12: spd_pre = x . Cqk^T; epilogue softplus->log->bf16 + norms
// ---------------------------------------------------------------------------
__global__ __launch_bounds__(256)
void proj_kernel(const unsigned short* __restrict__ X,
                 const unsigned short* __restrict__ Wv,
                 const unsigned short* __restrict__ Cqk,
                 const float* __restrict__ sqb, const float* __restrict__ skb,
                 unsigned short* __restrict__ vt,
                 unsigned short* __restrict__ lqo, unsigned short* __restrict__ lko,
                 float* __restrict__ nqo, float* __restrict__ nko)
{
    __shared__ unsigned short As[64*64];    // 8 KB, swizzled
    __shared__ unsigned short Bs[64*64];    // 8 KB, swizzled
    const int tid  = threadIdx.x;
    const int lane = tid & 63;
    const int qr   = lane & 15, quad = lane >> 4;
    const int wid  = tid >> 6;
    const int w_m  = wid >> 1, w_n = wid & 1;
    const int bx = blockIdx.x, by = blockIdx.y;

    const bool vrole = (bx < 12);
    const unsigned short* Abase = vrole ? (Wv + bx*64*768) : (X + by*64*768);
    const unsigned short* Bbase = vrole ? (X + by*64*768)  : (Cqk + (bx-12)*64*768);

    f32x4 acc[2][2] = {};

    for (int kt = 0; kt < 768; kt += 64) {
        __syncthreads();
        #pragma unroll
        for (int u = 0; u < 2; ++u) {
            const int slot = tid + u*256;
            const int srow = slot >> 3;
            const int sg = ((slot & 7) ^ (srow & 7)) << 3;
            __builtin_amdgcn_global_load_lds(AS_GLOBAL(Abase + srow*768 + kt + sg),
                                             AS_LDS(&As[slot*8]), 16, 0, 0);
            __builtin_amdgcn_global_load_lds(AS_GLOBAL(Bbase + srow*768 + kt + sg),
                                             AS_LDS(&Bs[slot*8]), 16, 0, 0);
        }
        __syncthreads();

        bf16x8 a[2][2], b[2][2];
        #pragma unroll
        for (int mi = 0; mi < 2; ++mi) {
            const int row = w_m*32 + mi*16 + qr;
            #pragma unroll
            for (int ks = 0; ks < 2; ++ks)
                a[mi][ks] = *(const bf16x8*)&As[(row << 6) + (((ks*4 + quad) ^ (row & 7)) << 3)];
        }
        #pragma unroll
        for (int ni = 0; ni < 2; ++ni) {
            const int row = w_n*32 + ni*16 + qr;
            #pragma unroll
            for (int ks = 0; ks < 2; ++ks)
                b[ni][ks] = *(const bf16x8*)&Bs[(row << 6) + (((ks*4 + quad) ^ (row & 7)) << 3)];
        }
        #pragma unroll
        for (int mi = 0; mi < 2; ++mi)
            #pragma unroll
            for (int ni = 0; ni < 2; ++ni)
                #pragma unroll
                for (int ks = 0; ks < 2; ++ks)
                    acc[mi][ni] = __builtin_amdgcn_mfma_f32_16x16x32_bf16(a[mi][ks], b[ni][ks], acc[mi][ni], 0, 0, 0);
    }

    if (vrole) {
        const int bidx = (by*64) >> 10;              // batch (uniform per by)
        #pragma unroll
        for (int mi = 0; mi < 2; ++mi) {
            #pragma unroll
            for (int r = 0; r < 4; ++r) {
                const int i = bx*64 + w_m*32 + mi*16 + quad*4 + r;  // V channel
                const int h = i >> 6, d = i & 63;
                #pragma unroll
                for (int ni = 0; ni < 2; ++ni) {
                    const int n = by*64 + w_n*32 + ni*16 + qr;      // seq (global)
                    vt[((((bidx*HQ + h) << 6) + d) << 10) + (n & 1023)] = f2bf(acc[mi][ni][r]);
                }
            }
        }
    } else {
        const int rr = qr & 7;
        #pragma unroll
        for (int ni = 0; ni < 2; ++ni) {
            const int c = (bx-12)*64 + w_n*32 + ni*16 + qr;   // 0..191
            const int g = (c >= 96);                          // uniform per 16-grp
            const int cc = c - g*96;
            const int h = cc >> 3;
            unsigned short* dst = g ? lko : lqo;
            float* ndst = g ? nko : nqo;
            const float bias = (g ? skb : sqb)[rr];
            #pragma unroll
            for (int mi = 0; mi < 2; ++mi) {
                #pragma unroll
                for (int r = 0; r < 4; ++r) {
                    const int m = by*64 + w_m*32 + mi*16 + quad*4 + r;
                    const int b = m >> 10, n = m & 1023;
                    const float pre = acc[mi][ni][r] + bias;
                    const float sp = (pre > 0.f) ? (pre + log1pf(__expf(-pre)))
                                                 : log1pf(__expf(pre));
                    const float l = __logf(sp + 1e-6f + 1e-8f);
                    const unsigned short lb = f2bf(l);
                    const int base = ((b*HQ + h) << 10) + n;
                    dst[(base << 3) + rr] = lb;
                    const float lr = bf2f(lb);
                    float sq = lr * lr;
                    sq += __shfl_xor(sq, 1);
                    sq += __shfl_xor(sq, 2);
                    sq += __shfl_xor(sq, 4);
                    if (rr == 0) ndst[base] = sq;
                }
            }
        }
    }
}

// ---------------------------------------------------------------------------
// O-proj GEMM, 64x64 tiles, grid (12,64), BK=64 swizzled (12 drains).
// out fp32 + bias; block (0,0) reduces the 256 KL partials and writes scalar.
// ---------------------------------------------------------------------------
__global__ __launch_bounds__(256)
void ogemm_kernel(const unsigned short* __restrict__ X,
                  const unsigned short* __restrict__ Wf,
                  const float* __restrict__ bias, float* __restrict__ outp,
                  const double* __restrict__ klparts)
{
    __shared__ unsigned short As[64*64];
    __shared__ unsigned short Bs[64*64];
    __shared__ double sd[256];
    const int tid  = threadIdx.x;
    const int lane = tid & 63;
    const int qr   = lane & 15, quad = lane >> 4;
    const int wid  = tid >> 6;
    const int w_m  = wid >> 1, w_n = wid & 1;
    const int bx = blockIdx.x, by = blockIdx.y;

    const unsigned short* Abase = X  + by*64*768;
    const unsigned short* Bbase = Wf + bx*64*768;

    f32x4 acc[2][2] = {};

    for (int kt = 0; kt < 768; kt += 64) {
        __syncthreads();
        #pragma unroll
        for (int u = 0; u < 2; ++u) {
            const int slot = tid + u*256;
            const int srow = slot >> 3;
            const int sg = ((slot & 7) ^ (srow & 7)) << 3;
            __builtin_amdgcn_global_load_lds(AS_GLOBAL(Abase + srow*768 + kt + sg),
                                             AS_LDS(&As[slot*8]), 16, 0, 0);
            __builtin_amdgcn_global_load_lds(AS_GLOBAL(Bbase + srow*768 + kt + sg),
                                             AS_LDS(&Bs[slot*8]), 16, 0, 0);
        }
        __syncthreads();

        bf16x8 a[2][2], b[2][2];
        #pragma unroll
        for (int mi = 0; mi < 2; ++mi) {
            const int row = w_m*32 + mi*16 + qr;
            #pragma unroll
            for (int ks = 0; ks < 2; ++ks)
                a[mi][ks] = *(const bf16x8*)&As[(row << 6) + (((ks*4 + quad) ^ (row & 7)) << 3)];
        }
        #pragma unroll
        for (int ni = 0; ni < 2; ++ni) {
            const int row = w_n*32 + ni*16 + qr;
            #pragma unroll
            for (int ks = 0; ks < 2; ++ks)
                b[ni][ks] = *(const bf16x8*)&Bs[(row << 6) + (((ks*4 + quad) ^ (row & 7)) << 3)];
        }
        #pragma unroll
        for (int mi = 0; mi < 2; ++mi)
            #pragma unroll
            for (int ni = 0; ni < 2; ++ni)
                #pragma unroll
                for (int ks = 0; ks < 2; ++ks)
                    acc[mi][ni] = __builtin_amdgcn_mfma_f32_16x16x32_bf16(a[mi][ks], b[ni][ks], acc[mi][ni], 0, 0, 0);
    }

    #pragma unroll
    for (int ni = 0; ni < 2; ++ni) {
        const int i = bx*64 + w_n*32 + ni*16 + qr;
        const float bs = bias[i];
        #pragma unroll
        for (int mi = 0; mi < 2; ++mi) {
            const int m0 = by*64 + w_m*32 + mi*16 + quad*4;
            #pragma unroll
            for (int r = 0; r < 4; ++r)
                outp[(m0 + r)*768 + i] = acc[mi][ni][r] + bs;
        }
    }

    if (bx == 0 && by == 0) {
        sd[tid] = klparts[tid];
        __syncthreads();
        for (int s = 128; s > 0; s >>= 1) {
            if (tid < s) sd[tid] += sd[tid + s];
            __syncthreads();
        }
        if (tid == 0) outp[OUT_ELEMS] = (float)(0.5 * sd[0]);
    }
}

// ---------------------------------------------------------------------------
// Attention (R12's proven version): 256 threads, 64 queries/block, 128-key
// chunks (8 drains). LDS: lk 2 KB + vt 16 KB swizzled + w_s 64x136.
// ---------------------------------------------------------------------------
__global__ __launch_bounds__(256)
void attn_kernel(const unsigned short* __restrict__ lq,
                 const unsigned short* __restrict__ lk,
                 const float* __restrict__ nq, const float* __restrict__ nk,
                 const unsigned short* __restrict__ vt,
                 unsigned short* __restrict__ out)
{
    __shared__ unsigned short lk_s[128*8];    // 2 KB
    __shared__ unsigned short vt_s[64*128];   // 16 KB, swizzled 16B groups
    __shared__ unsigned short w_s[64*136];    // 17 KB, stride 136

    const int tid  = threadIdx.x;
    const int lane = tid & 63;
    const int wid  = tid >> 6;
    const int qr   = lane & 15;
    const int quad = lane >> 4;
    const int bh   = blockIdx.y;
    const int q0   = blockIdx.x*64 + wid*16;
    const int qrow = (bh << 10) + q0 + qr;
    const int bb   = bh / HQ;
    const int hh   = bh - bb*HQ;

    bf16x8 bq = {};
    if (quad == 0) bq = *(const bf16x8*)(lq + qrow*8);
    const float nqv = nq[qrow];

    f32x4 acc[4] = {};
    float wsum_acc = 0.f;

    const unsigned short* vtg = vt + (bh << 16);   // bh*64*1024
    const unsigned short* lkg = lk + (bh << 13);   // bh*1024*8
    const float*          nkg = nk + (bh << 10);

    const float EXP2S = -0.1803368801f;            // -0.125 * log2(e)

    for (int c = 0; c < NSEQ; c += 128) {
        __syncthreads();
        #pragma unroll
        for (int u = 0; u < 4; ++u) {
            const int slot = tid + u*256;
            const int srow = slot >> 4;
            const int gg = ((slot & 15) ^ (srow & 7)) << 3;   // global col elem
            __builtin_amdgcn_global_load_lds(AS_GLOBAL(vtg + srow*1024 + c + gg),
                                             AS_LDS(&vt_s[slot*8]), 16, 0, 0);
        }
        if (tid < 128)
            __builtin_amdgcn_global_load_lds(AS_GLOBAL(lkg + (c + tid)*8),
                                             AS_LDS(&lk_s[tid*8]), 16, 0, 0);
        __syncthreads();

        float wsum_c = 0.f;
        unsigned wpk[8][2];
        #pragma unroll
        for (int kb = 0; kb < 8; ++kb) {
            bf16x8 ak = {};
            if (quad == 0) ak = *(const bf16x8*)&lk_s[(kb*16 + qr)*8];
            f32x4 s = {};
            s = __builtin_amdgcn_mfma_f32_16x16x32_bf16(ak, bq, s, 0, 0, 0);
            const float4 nk4 = *(const float4*)(nkg + c + kb*16 + quad*4);
            const float nkv[4] = {nk4.x, nk4.y, nk4.z, nk4.w};
            float w[4];
            #pragma unroll
            for (int r = 0; r < 4; ++r) {
                const float d2 = fmaf(-2.f, s[r], nqv + nkv[r]);
                const float dist = __builtin_amdgcn_sqrtf(fmaxf(d2, 1e-12f));
                w[r] = exp2f(dist * EXP2S);
                wsum_c += w[r];
            }
            wpk[kb][0] = pack_bf16(w[0], w[1]);
            wpk[kb][1] = pack_bf16(w[2], w[3]);
        }
        #pragma unroll
        for (int kb = 0; kb < 8; ++kb)
            *(uint2*)&w_s[(wid*16 + qr)*136 + kb*16 + quad*4] =
                make_uint2(wpk[kb][0], wpk[kb][1]);
        wsum_c += __shfl_xor(wsum_c, 16);
        wsum_c += __shfl_xor(wsum_c, 32);
        wsum_acc += wsum_c;

        #pragma unroll
        for (int s2 = 0; s2 < 4; ++s2) {
            const bf16x8 af = *(const bf16x8*)&w_s[(wid*16 + qr)*136 + s2*32 + quad*8];
            #pragma unroll
            for (int jb = 0; jb < 4; ++jb) {
                const int row = jb*16 + qr;
                const int grp = (s2*4 + quad) ^ (qr & 7);
                const bf16x8 bv = *(const bf16x8*)&vt_s[(row << 7) + (grp << 3)];
                acc[jb] = __builtin_amdgcn_mfma_f32_16x16x32_bf16(af, bv, acc[jb], 0, 0, 0);
            }
        }
    }

    const float inv = 1.0f / wsum_acc;   // lane's own q = qr
    #pragma unroll
    for (int jb = 0; jb < 4; ++jb) {
        #pragma unroll
        for (int r = 0; r < 4; ++r) {
            const int row = quad*4 + r;
            const float wi = __shfl(inv, row);
            const int qgl = q0 + row;
            const int d = jb*16 + qr;
            out[((bb << 10) + qgl)*768 + hh*64 + d] = f2bf(acc[jb][r] * wi);
        }
    }
}

// ---------------------------------------------------------------------------
extern "C" void kernel_launch(void* const* d_in, const int* in_sizes, int n_in,
                              void* d_out, int out_size, void* d_ws, size_t ws_size,
                              hipStream_t stream)
{
    const float* x     = (const float*)d_in[0];
    const float* wq    = (const float*)d_in[1];
    const float* wq_ls = (const float*)d_in[2];
    const float* wk    = (const float*)d_in[3];
    const float* wk_ls = (const float*)d_in[4];
    const float* wv    = (const float*)d_in[5];
    const float* wv_ls = (const float*)d_in[6];
    const float* wo    = (const float*)d_in[7];
    const float* wo_ls = (const float*)d_in[8];
    const float* wo_b  = (const float*)d_in[9];
    const float* sq_w  = (const float*)d_in[10];
    const float* sq_b  = (const float*)d_in[11];
    const float* sk_w  = (const float*)d_in[12];
    const float* sk_b  = (const float*)d_in[13];
    float* out = (float*)d_out;

    float* ws = (float*)d_ws;
    unsigned short* vt  = (unsigned short*)ws;                 // 1572864 f
    unsigned short* xb  = (unsigned short*)(ws + 1572864);     // 1572864 f (re-used as attn out)
    unsigned short* wvb = (unsigned short*)(ws + 3145728);     // 294912 f
    unsigned short* wob = (unsigned short*)(ws + 3440640);     // 294912 f
    unsigned short* cqk = (unsigned short*)(ws + 3735552);     // 73728 f
    unsigned short* lqb = (unsigned short*)(ws + 3809280);     // 196608 f
    unsigned short* lkb = (unsigned short*)(ws + 4005888);     // 196608 f
    float* nqb = ws + 4202496;                                 // 49152 f
    float* nkb = ws + 4251648;                                 // 49152 f
    double* klparts = (double*)(ws + 4300800);                 // 256 doubles

    prep_kernel<<<dim3(576, 8), dim3(256), 0, stream>>>(
        x, wv, wo, wq, wq_ls, wk, wk_ls, wv_ls, wo_ls, sq_w, sk_w,
        xb, wvb, wob, cqk, klparts);
    proj_kernel<<<dim3(15, 64), dim3(256), 0, stream>>>(xb, wvb, cqk, sq_b, sk_b,
                                                        vt, lqb, lkb, nqb, nkb);
    attn_kernel<<<dim3(16, BHD), dim3(256), 0, stream>>>(lqb, lkb, nqb, nkb, vt, xb);
    ogemm_kernel<<<dim3(12, 64), dim3(256), 0, stream>>>(xb, wob, wo_b, out, klparts);
}